// Round 13
// baseline (356.968 us; speedup 1.0000x reference)
//
#include <hip/hip_runtime.h>
#include <stdint.h>

// Problem constants
// B=2, T=24, N=512, D=128, P=16, HD=16; SCALE=0.25
// temporal arrays layout [B,N,2,24,16]; spatial [B,T,H,N,16]

static const size_t OFF_WP   = 0;                      // f16 B-frag weights: uint2[38*8*64]
static const size_t TSZ      = 786432;                 // 2*512*2*24*16
static const size_t GSZ      = 1572864;                // 2*24*4*512*16
static const size_t OFF_T0   = 81920;                  // 7 temporal arrays (tq,tk,tv,rtv,tubq,tubk,tubv)
static const size_t OFF_GEOQ = OFF_T0 + 7*TSZ;         // geo q,k,v each GSZ
static const size_t OFF_GEOK = OFF_GEOQ + GSZ;
static const size_t OFF_GEOV = OFF_GEOK + GSZ;
static const size_t OFF_SEM  = OFF_GEOQ + 3*GSZ;       // sem q,k,v each TSZ
static const size_t OFF_RND  = OFF_SEM + 3*TSZ;        // rnd q,k,v each TSZ
static const size_t OFF_PQ   = OFF_RND + 3*TSZ;        // [24576][64]; becomes k_add in-place
static const size_t OFF_PK   = OFF_PQ + GSZ;           // [768][64]
static const size_t OFF_PV   = OFF_PK + 49152;
static const size_t OFF_CAT  = OFF_PV + 49152;         // [24576][224]
static const size_t OFF_MB   = OFF_CAT + 24576ull*224; // 3*512*16 u32 mask words
static const size_t OFF_WP2  = OFF_MB + 24576;         // f16 B-frag proj_w: uint2[8*14*64]

using f32x4 = __attribute__((ext_vector_type(4))) float;
using f16x4 = __attribute__((ext_vector_type(4))) _Float16;

struct PackPtrs {
    const float* w[16];
    const float* pw;      // proj_w [224][128]
    const void* msk[3];
};

// ---------------------------------------------------------------------------
// K0: pack weights as f16 MFMA B-fragments (validated layout):
//   wb [(nt*8 +kt)*64+l] = {Wp[kt*16+(l>>4)*4+i][nt*16+(l&15)]}  (608-col fused W)
//   wb2[(nt*14+kt)*64+l] = {proj_w[kt*16+(l>>4)*4+i][nt*16+(l&15)]}
// + bit-pack masks (4-byte vs 1-byte encoding sniff over 16 words; validated).
// ---------------------------------------------------------------------------
__global__ __launch_bounds__(256) void pack_kernel(PackPtrs pp, float* __restrict__ ws) {
    int tid = blockIdx.x * 256 + threadIdx.x;
    if (tid < 20480) {
        int l = tid & 63, kt = (tid >> 6) & 7, nt = tid >> 9;
        int k0 = kt * 16 + ((l >> 4) << 2);
        int c  = nt * 16 + (l & 15);
        f16x4 h;
        #pragma unroll
        for (int i = 0; i < 4; i++) {
            float v = 0.f;
            int kk = k0 + i;
            if (c < 224) {              // 7 temporal mats, each D x 32
                int which = c >> 5, col = c & 31;
                v = pp.w[which][kk * 32 + col];
            } else if (c < 416) {       // geo q,k,v, each D x 64
                int cc = c - 224; int which = 7 + (cc >> 6), col = cc & 63;
                v = pp.w[which][kk * 64 + col];
            } else if (c < 608) {       // sem q,k,v + rnd q,k,v, each D x 32
                int cc = c - 416; int which = 10 + (cc >> 5), col = cc & 31;
                v = pp.w[which][kk * 32 + col];
            }
            h[i] = (_Float16)v;
        }
        ((uint2*)(ws + OFF_WP))[tid] = *(uint2*)&h;
    } else if (tid < 27648) {
        int u = tid - 20480;            // 7168 = 8 nt * 14 kt * 64
        int l = u & 63, kt = (u >> 6) % 14, nt = u / 896;
        int k0 = kt * 16 + ((l >> 4) << 2);
        int c  = nt * 16 + (l & 15);
        f16x4 h;
        #pragma unroll
        for (int i = 0; i < 4; i++) h[i] = (_Float16)pp.pw[(size_t)(k0 + i) * 128 + c];
        ((uint2*)(ws + OFF_WP2))[u] = *(uint2*)&h;
    } else {
        int w = tid - 27648;
        if (w < 3 * 8192) {
            int mi = w / 8192, rem = w % 8192;
            int base = (rem >> 4) * 512 + (rem & 15) * 32;   // element index of bit 0
            const uint32_t* w32 = (const uint32_t*)pp.msk[mi];
            uint32_t hibytes = 0;      // nonzero => not int32 0/1
            int isfloat = 1;           // stays 1 => every word is 0.0f or 1.0f
            #pragma unroll
            for (int i = 0; i < 16; i++) {
                uint32_t wv = w32[i];
                hibytes |= wv & 0xFFFFFF00u;
                if (wv != 0u && wv != 0x3F800000u) isfloat = 0;
            }
            uint32_t bits = 0;
            if (isfloat || hibytes == 0) {   // 4-byte elements: word != 0 is truth
                const uint32_t* s = w32 + base;
                #pragma unroll
                for (int j = 0; j < 32; j++) bits |= (s[j] != 0u ? 1u : 0u) << j;
            } else {                          // 1-byte elements
                const uint8_t* s = (const uint8_t*)pp.msk[mi] + base;
                #pragma unroll
                for (int j = 0; j < 32; j++) bits |= (s[j] ? 1u : 0u) << j;
            }
            ((uint32_t*)(ws + OFF_MB))[w] = bits;
        }
    }
}

// ---------------------------------------------------------------------------
// K1 (MFMA): projection x[24576x128] @ W[128x608] -> scatter (validated r9).
// ---------------------------------------------------------------------------
__global__ __launch_bounds__(256) void proj_gemm_mfma(const float* __restrict__ x,
                                                      float* __restrict__ ws) {
    int rb = blockIdx.x * 64;
    int t = threadIdx.x, lane = t & 63, w = t >> 6;
    int lr = lane & 15, lg4 = (lane >> 4) * 4;
    int bt = rb >> 9;                   // block-uniform
    int rt_ = bt % 24, rbq = bt / 24;
    int rnb = (rb & 511) + lg4;         // rn = rnb + rt*16 + i

    f16x4 af[4][8];
    #pragma unroll
    for (int rt = 0; rt < 4; rt++)
        #pragma unroll
        for (int kt = 0; kt < 8; kt++) {
            float4 v = *(const float4*)(x + (size_t)(rb + rt * 16 + lr) * 128 + kt * 16 + lg4);
            f16x4 h;
            h[0] = (_Float16)v.x; h[1] = (_Float16)v.y;
            h[2] = (_Float16)v.z; h[3] = (_Float16)v.w;
            af[rt][kt] = h;
        }
    const uint2* wb = (const uint2*)(ws + OFF_WP);
    const f32x4 zero4 = {0.f, 0.f, 0.f, 0.f};
    for (int j = 0; j < 10; j++) {
        int nt = w * 10 + j;
        if (nt >= 38) break;
        f16x4 bf[8];
        #pragma unroll
        for (int kt = 0; kt < 8; kt++) {
            uint2 u = wb[(size_t)(nt * 8 + kt) * 64 + lane];
            bf[kt] = *(f16x4*)&u;
        }
        f32x4 acc[4] = {zero4, zero4, zero4, zero4};
        #pragma unroll
        for (int kt = 0; kt < 8; kt++)
            #pragma unroll
            for (int rt = 0; rt < 4; rt++)
                acc[rt] = __builtin_amdgcn_mfma_f32_16x16x16f16(af[rt][kt], bf[kt], acc[rt], 0, 0, 0);
        size_t base; int str;
        if (nt < 14) {
            int which = nt >> 1, h = nt & 1;
            base = OFF_T0 + (size_t)which * TSZ + ((size_t)rbq * 24576 + h * 24 + rt_) * 16;
            str = 768;
        } else if (nt < 26) {
            int g = (nt - 14) >> 2, h = (nt - 14) & 3;
            base = OFF_GEOQ + (size_t)g * GSZ + (size_t)(bt * 4 + h) * 8192;
            str = 16;
        } else {
            int np = nt - 26; int isr = np >= 6; int npp = np - (isr ? 6 : 0);
            int g = npp >> 1, h = npp & 1;
            base = (isr ? OFF_RND : OFF_SEM) + (size_t)g * TSZ + (size_t)(bt * 2 + h) * 8192;
            str = 16;
        }
        #pragma unroll
        for (int rt = 0; rt < 4; rt++) {
            int rn0 = rnb + rt * 16;
            #pragma unroll
            for (int i = 0; i < 4; i++)
                ws[base + (size_t)(rn0 + i) * str + lr] = acc[rt][i];
        }
    }
}

// ---------------------------------------------------------------------------
// K2 (MFMA): final projection cat[24576x224] @ proj_w[224x128] + bias -> out.
// Block 64 rows, 4 waves; wave handles 2 col-tiles over full K (14 kt).
// A-frags reloaded per nt (L1-resident); low VGPR -> high occupancy.
// ---------------------------------------------------------------------------
__global__ __launch_bounds__(256) void final_gemm_mfma(const float* __restrict__ bias,
                                                       float* __restrict__ ws,
                                                       float* __restrict__ out) {
    int rb = blockIdx.x * 64;
    int t = threadIdx.x, lane = t & 63, w = t >> 6;
    int lr = lane & 15, lg4 = (lane >> 4) * 4;
    const float* A = ws + OFF_CAT;
    const uint2* wb2 = (const uint2*)(ws + OFF_WP2);
    const f32x4 zero4 = {0.f, 0.f, 0.f, 0.f};
    #pragma unroll
    for (int j = 0; j < 2; j++) {
        int nt = w * 2 + j;
        float bv = bias[nt * 16 + lr];
        f32x4 acc[4] = {zero4, zero4, zero4, zero4};
        #pragma unroll
        for (int kt = 0; kt < 14; kt++) {
            uint2 u = wb2[(size_t)(nt * 14 + kt) * 64 + lane];
            f16x4 bf = *(f16x4*)&u;
            #pragma unroll
            for (int rt = 0; rt < 4; rt++) {
                float4 v = *(const float4*)(A + (size_t)(rb + rt * 16 + lr) * 224 + kt * 16 + lg4);
                f16x4 h;
                h[0] = (_Float16)v.x; h[1] = (_Float16)v.y;
                h[2] = (_Float16)v.z; h[3] = (_Float16)v.w;
                acc[rt] = __builtin_amdgcn_mfma_f32_16x16x16f16(h, bf, acc[rt], 0, 0, 0);
            }
        }
        #pragma unroll
        for (int rt = 0; rt < 4; rt++)
            #pragma unroll
            for (int i = 0; i < 4; i++)
                out[(size_t)(rb + rt * 16 + lg4 + i) * 128 + nt * 16 + lr] = acc[rt][i] + bv;
    }
}

// ---------------------------------------------------------------------------
// Generic tiled GEMM (pq/pk/pv): C[M][N] = A[M][K] @ W[K][N] (+bias).
// ---------------------------------------------------------------------------
__global__ __launch_bounds__(256, 4) void gemm_tile(const float* __restrict__ A,
                                                    const float* __restrict__ W,
                                                    const float* __restrict__ bias,
                                                    float* __restrict__ C,
                                                    int K, int N) {
    __shared__ float a_t[32][68];
    __shared__ float bs[32][64];
    int rb = blockIdx.x * 64, cb = blockIdx.y * 64;
    int t = threadIdx.x, tr = t & 15, tc = t >> 4;
    float acc[4][4] = {{0.f}};
    for (int k0 = 0; k0 < K; k0 += 32) {
        __syncthreads();
        for (int f = t; f < 512; f += 256) {
            int r = f >> 3, kc = f & 7;
            float4 v = *(const float4*)(A + (size_t)(rb + r) * K + k0 + kc * 4);
            a_t[kc * 4 + 0][r] = v.x; a_t[kc * 4 + 1][r] = v.y;
            a_t[kc * 4 + 2][r] = v.z; a_t[kc * 4 + 3][r] = v.w;
        }
        for (int f = t; f < 512; f += 256) {
            int kk = f >> 4, cc = f & 15;
            *(float4*)&bs[kk][cc * 4] = *(const float4*)(W + (size_t)(k0 + kk) * N + cb + cc * 4);
        }
        __syncthreads();
        #pragma unroll
        for (int kk = 0; kk < 32; kk++) {
            float4 a4 = *(const float4*)&a_t[kk][tr * 4];
            float4 b4 = *(const float4*)&bs[kk][tc * 4];
            float av[4] = {a4.x, a4.y, a4.z, a4.w};
            float bv[4] = {b4.x, b4.y, b4.z, b4.w};
            #pragma unroll
            for (int i = 0; i < 4; i++)
                #pragma unroll
                for (int j = 0; j < 4; j++) acc[i][j] += av[i] * bv[j];
        }
    }
    #pragma unroll
    for (int i = 0; i < 4; i++) {
        int row = rb + tr * 4 + i, col = cb + tc * 4;
        float4 o = make_float4(acc[i][0], acc[i][1], acc[i][2], acc[i][3]);
        if (bias) {
            o.x += bias[col]; o.y += bias[col + 1];
            o.z += bias[col + 2]; o.w += bias[col + 3];
        }
        *(float4*)(C + (size_t)row * N + col) = o;
    }
}

// ---------------------------------------------------------------------------
// K3: pattern attention -> k_add IN-PLACE over PQ (validated r9).
// ---------------------------------------------------------------------------
__global__ __launch_bounds__(256) void pattern_kadd(float* __restrict__ ws) {
    __shared__ float pk[16][64];
    __shared__ float pv[16][64];
    int bt = blockIdx.x, t = threadIdx.x;
    {
        int p = t >> 4, cc = t & 15;
        *(float4*)&pk[p][cc * 4] = *(const float4*)(ws + OFF_PK + (size_t)bt * 1024 + p * 64 + cc * 4);
        *(float4*)&pv[p][cc * 4] = *(const float4*)(ws + OFF_PV + (size_t)bt * 1024 + p * 64 + cc * 4);
    }
    __syncthreads();
    int n = blockIdx.y * 256 + t;
    float* pqr = ws + OFF_PQ + ((size_t)bt * 512 + n) * 64;
    float s[16];
    #pragma unroll
    for (int p = 0; p < 16; p++) s[p] = 0.f;
    #pragma unroll
    for (int j = 0; j < 16; j++) {
        float4 q4 = *(const float4*)(pqr + j * 4);
        #pragma unroll
        for (int p = 0; p < 16; p++) {
            float4 k4 = *(const float4*)&pk[p][j * 4];
            s[p] += q4.x * k4.x + q4.y * k4.y + q4.z * k4.z + q4.w * k4.w;
        }
    }
    float mx = -3e38f;
    #pragma unroll
    for (int p = 0; p < 16; p++) { s[p] *= 0.25f; mx = fmaxf(mx, s[p]); }
    float l = 0.f;
    #pragma unroll
    for (int p = 0; p < 16; p++) { s[p] = __expf(s[p] - mx); l += s[p]; }
    float inv = 1.f / l;
    #pragma unroll
    for (int p = 0; p < 16; p++) s[p] *= inv;
    #pragma unroll
    for (int j = 0; j < 16; j++) {
        float ax = 0.f, ay = 0.f, az = 0.f, aw = 0.f;
        #pragma unroll
        for (int p = 0; p < 16; p++) {
            float4 v4 = *(const float4*)&pv[p][j * 4];
            ax += s[p] * v4.x; ay += s[p] * v4.y; az += s[p] * v4.z; aw += s[p] * v4.w;
        }
        *(float4*)(pqr + j * 4) = make_float4(ax, ay, az, aw);
    }
}

// ---------------------------------------------------------------------------
// K4 (MFMA): spatial attention (validated r8/r9); softmax in log2 domain
// (fold 0.25*log2e into Q, exp2f == native v_exp_f32).
// ---------------------------------------------------------------------------
__global__ __launch_bounds__(256) void spatial_attn_mfma(float* __restrict__ ws) {
    __shared__ uint2 ldsK[2048];  // slot[ct*64+l] = K[ct*16+(l&15)][(l>>4)*4+0..3] f16
    __shared__ uint2 ldsV[2048];  // slot[ct*64+l] = V[ct*16+(l>>4)*4+0..3][l&15] f16
    int blk = blockIdx.x;
    int inst = blk >> 1, qhalf = blk & 1;
    int hg = inst & 7, bt = inst >> 3;
    size_t qoff, koff, voff;
    const uint32_t* mbase = (const uint32_t*)(ws + OFF_MB);
    const uint32_t* mb;
    int cbase;
    if (hg < 4) {
        size_t hb = ((size_t)bt * 4 + hg) * 8192;
        qoff = OFF_GEOQ + hb; koff = OFF_GEOK + hb; voff = OFF_GEOV + hb;
        mb = mbase; cbase = 32 + hg * 16;
    } else if (hg < 6) {
        int h = hg - 4; size_t hb = ((size_t)bt * 2 + h) * 8192;
        qoff = OFF_SEM + hb; koff = OFF_SEM + TSZ + hb; voff = OFF_SEM + 2 * TSZ + hb;
        mb = mbase + 8192; cbase = 96 + h * 16;
    } else {
        int h = hg - 6; size_t hb = ((size_t)bt * 2 + h) * 8192;
        qoff = OFF_RND + hb; koff = OFF_RND + TSZ + hb; voff = OFF_RND + 2 * TSZ + hb;
        mb = mbase + 16384; cbase = 128 + h * 16;
    }
    int t = threadIdx.x;
    // --- stage K (A-frag layout), geo adds k_add ---
    {
        const float* Kg = ws + koff;
        const float* KA = ws + OFF_PQ + ((size_t)bt * 512) * 64 + hg * 16;  // valid iff hg<4
        for (int s = t; s < 2048; s += 256) {
            int l = s & 63;
            int row = ((s >> 6) << 4) + (l & 15), dg = (l >> 4) * 4;
            float4 v = *(const float4*)(Kg + (size_t)row * 16 + dg);
            if (hg < 4) {
                float4 a = *(const float4*)(KA + (size_t)row * 64 + dg);
                v.x += a.x; v.y += a.y; v.z += a.z; v.w += a.w;
            }
            f16x4 h;
            h[0] = (_Float16)v.x; h[1] = (_Float16)v.y;
            h[2] = (_Float16)v.z; h[3] = (_Float16)v.w;
            ldsK[s] = *(uint2*)&h;
        }
    }
    // --- stage V (B-frag layout: k-transposed) ---
    {
        const float* Vg = ws + voff;
        for (int s = t; s < 2048; s += 256) {
            int l = s & 63;
            int dcol = l & 15, rb = ((s >> 6) << 4) + (l >> 4) * 4;
            f16x4 h;
            h[0] = (_Float16)Vg[(size_t)(rb + 0) * 16 + dcol];
            h[1] = (_Float16)Vg[(size_t)(rb + 1) * 16 + dcol];
            h[2] = (_Float16)Vg[(size_t)(rb + 2) * 16 + dcol];
            h[3] = (_Float16)Vg[(size_t)(rb + 3) * 16 + dcol];
            ldsV[s] = *(uint2*)&h;
        }
    }
    __syncthreads();
    int lane = t & 63, wave = t >> 6;
    int lq = lane & 15, lg = lane >> 4;
    const float* Qg = ws + qoff;
    float* cat = ws + OFF_CAT;
    const f32x4 zero4 = {0.f, 0.f, 0.f, 0.f};
    const float QS = 0.25f * 1.44269504f;   // SCALE * log2(e)
    for (int jt = 0; jt < 4; jt++) {
        int qt = qhalf * 16 + wave * 4 + jt;   // global q-tile 0..31
        int q = qt * 16 + lq;                  // this lane's softmax row
        float4 qv = *(const float4*)(Qg + (size_t)q * 16 + lg * 4);
        f16x4 qf;                              // pre-scaled: scores in log2 domain
        qf[0] = (_Float16)(qv.x * QS); qf[1] = (_Float16)(qv.y * QS);
        qf[2] = (_Float16)(qv.z * QS); qf[3] = (_Float16)(qv.w * QS);
        f32x4 O = zero4;
        float m = -3e38f, lsum = 0.f;
        const uint32_t* mrow = mb + (size_t)q * 16;
        for (int ch = 0; ch < 4; ch++) {
            uint4 mw = *(const uint4*)(mrow + ch * 4);
            float p[8][4];
            float cm = -3e38f;
            #pragma unroll
            for (int c8 = 0; c8 < 8; c8++) {
                int ct = ch * 8 + c8;
                uint2 kslot = ldsK[ct * 64 + lane];
                f16x4 kf = *(f16x4*)&kslot;
                f32x4 sres = __builtin_amdgcn_mfma_f32_16x16x16f16(kf, qf, zero4, 0, 0, 0);
                uint32_t w = ((const uint32_t*)&mw)[c8 >> 1];
                uint32_t nib = (w >> (((c8 & 1) << 4) + lg * 4)) & 0xFu;
                #pragma unroll
                for (int i = 0; i < 4; i++) {
                    float sv = ((nib >> i) & 1u) ? -1e30f : sres[i];
                    p[c8][i] = sv;
                    cm = fmaxf(cm, sv);
                }
            }
            cm = fmaxf(cm, __shfl_xor(cm, 16));
            cm = fmaxf(cm, __shfl_xor(cm, 32));
            float nm = fmaxf(m, cm);
            float scale = exp2f(m - nm);
            m = nm;
            float psum = 0.f;
            #pragma unroll
            for (int c8 = 0; c8 < 8; c8++)
                #pragma unroll
                for (int i = 0; i < 4; i++) {
                    float pv = exp2f(p[c8][i] - m);
                    p[c8][i] = pv; psum += pv;
                }
            lsum = lsum * scale + psum;
            #pragma unroll
            for (int i = 0; i < 4; i++) O[i] *= __shfl(scale, lg * 4 + i);
            #pragma unroll
            for (int c8 = 0; c8 < 8; c8++) {
                int ct = ch * 8 + c8;
                f16x4 pf;
                pf[0] = (_Float16)p[c8][0]; pf[1] = (_Float16)p[c8][1];
                pf[2] = (_Float16)p[c8][2]; pf[3] = (_Float16)p[c8][3];
                uint2 vslot = ldsV[ct * 64 + lane];
                f16x4 vf = *(f16x4*)&vslot;
                O = __builtin_amdgcn_mfma_f32_16x16x16f16(pf, vf, O, 0, 0, 0);
            }
        }
        lsum += __shfl_xor(lsum, 16);
        lsum += __shfl_xor(lsum, 32);
        #pragma unroll
        for (int i = 0; i < 4; i++) {
            float ls = __shfl(lsum, lg * 4 + i);
            int qrow = qt * 16 + lg * 4 + i;
            cat[((size_t)bt * 512 + qrow) * 224 + cbase + lq] = O[i] / ls;
        }
    }
}

// ---------------------------------------------------------------------------
// K5: temporal attention, branch-split: gid < 49152 -> t-branch (t_x & rt_x),
// else tube branch. 64-thread blocks x 1536 = 6 waves/CU; branch boundary is
// wave-aligned (49152 % 64 == 0) -> no divergence.
// ---------------------------------------------------------------------------
__global__ __launch_bounds__(64) void temporal_attn(float* __restrict__ ws) {
    int gid = blockIdx.x * 64 + threadIdx.x;   // 98304 total
    int branch = gid >= 49152;
    int tid = branch ? gid - 49152 : gid;
    int tt = tid % 24;
    int h  = (tid / 24) & 1;
    int n  = (tid / 48) & 511;
    int b  = tid / 24576;
    size_t base = (((size_t)b * 512 + n) * 2 + h) * 384;
    float* cat = ws + OFF_CAT + (((size_t)b * 24 + tt) * 512 + n) * 224;

    float q[16], p[24];
    if (!branch) {
        const float* TQ  = ws + OFF_T0 + 0 * TSZ + base;
        const float* TK  = ws + OFF_T0 + 1 * TSZ + base;
        const float* TV  = ws + OFF_T0 + 2 * TSZ + base;
        const float* RTV = ws + OFF_T0 + 3 * TSZ + base;
        #pragma unroll
        for (int j = 0; j < 4; j++) {
            float4 v = *(const float4*)(TQ + tt * 16 + j * 4);
            q[j*4+0] = v.x; q[j*4+1] = v.y; q[j*4+2] = v.z; q[j*4+3] = v.w;
        }
        float mx = -3e38f;
        #pragma unroll
        for (int s = 0; s < 24; s++) {
            float d = 0.f;
            #pragma unroll
            for (int j = 0; j < 4; j++) {
                float4 k4 = *(const float4*)(TK + s * 16 + j * 4);
                d += q[j*4+0]*k4.x + q[j*4+1]*k4.y + q[j*4+2]*k4.z + q[j*4+3]*k4.w;
            }
            d *= 0.25f; p[s] = d; mx = fmaxf(mx, d);
        }
        float l = 0.f;
        #pragma unroll
        for (int s = 0; s < 24; s++) { p[s] = __expf(p[s] - mx); l += p[s]; }
        float inv = 1.f / l;
        float a1[16], a2[16];
        #pragma unroll
        for (int d = 0; d < 16; d++) { a1[d] = 0.f; a2[d] = 0.f; }
        #pragma unroll
        for (int s = 0; s < 24; s++) {
            float w = p[s];
            #pragma unroll
            for (int j = 0; j < 4; j++) {
                float4 v4 = *(const float4*)(TV + s * 16 + j * 4);
                a1[j*4+0] += w*v4.x; a1[j*4+1] += w*v4.y; a1[j*4+2] += w*v4.z; a1[j*4+3] += w*v4.w;
                float4 r4 = *(const float4*)(RTV + s * 16 + j * 4);
                a2[j*4+0] += w*r4.x; a2[j*4+1] += w*r4.y; a2[j*4+2] += w*r4.z; a2[j*4+3] += w*r4.w;
            }
        }
        #pragma unroll
        for (int j = 0; j < 4; j++) {
            *(float4*)(cat + 0 + h * 16 + j * 4)   = make_float4(a1[j*4]*inv, a1[j*4+1]*inv, a1[j*4+2]*inv, a1[j*4+3]*inv);
            *(float4*)(cat + 160 + h * 16 + j * 4) = make_float4(a2[j*4]*inv, a2[j*4+1]*inv, a2[j*4+2]*inv, a2[j*4+3]*inv);
        }
    } else {
        const float* UQ  = ws + OFF_T0 + 4 * TSZ + base;
        const float* UK  = ws + OFF_T0 + 5 * TSZ + base;
        const float* UV  = ws + OFF_T0 + 6 * TSZ + base;
        #pragma unroll
        for (int j = 0; j < 4; j++) {
            float4 v = *(const float4*)(UQ + tt * 16 + j * 4);
            q[j*4+0] = v.x; q[j*4+1] = v.y; q[j*4+2] = v.z; q[j*4+3] = v.w;
        }
        float mx = -3e38f;
        #pragma unroll
        for (int s = 0; s < 24; s++) {
            float d = 0.f;
            #pragma unroll
            for (int j = 0; j < 4; j++) {
                float4 k4 = *(const float4*)(UK + s * 16 + j * 4);
                d += q[j*4+0]*k4.x + q[j*4+1]*k4.y + q[j*4+2]*k4.z + q[j*4+3]*k4.w;
            }
            d *= 0.25f; p[s] = d; mx = fmaxf(mx, d);
        }
        float l = 0.f;
        #pragma unroll
        for (int s = 0; s < 24; s++) { p[s] = __expf(p[s] - mx); l += p[s]; }
        float inv = 1.f / l;
        float a1[16];
        #pragma unroll
        for (int d = 0; d < 16; d++) a1[d] = 0.f;
        #pragma unroll
        for (int s = 0; s < 24; s++) {
            float w = p[s];
            #pragma unroll
            for (int j = 0; j < 4; j++) {
                float4 v4 = *(const float4*)(UV + s * 16 + j * 4);
                a1[j*4+0] += w*v4.x; a1[j*4+1] += w*v4.y; a1[j*4+2] += w*v4.z; a1[j*4+3] += w*v4.w;
            }
        }
        #pragma unroll
        for (int j = 0; j < 4; j++)
            *(float4*)(cat + 192 + h * 16 + j * 4) = make_float4(a1[j*4]*inv, a1[j*4+1]*inv, a1[j*4+2]*inv, a1[j*4+3]*inv);
    }
}

// ---------------------------------------------------------------------------
extern "C" void kernel_launch(void* const* d_in, const int* in_sizes, int n_in,
                              void* d_out, int out_size, void* d_ws, size_t ws_size,
                              hipStream_t stream) {
    const float* x     = (const float*)d_in[0];
    const float* xp    = (const float*)d_in[1];
    const float* pkeys = (const float*)d_in[2];
    float* ws  = (float*)d_ws;
    float* out = (float*)d_out;

    PackPtrs pp;
    pp.w[0]  = (const float*)d_in[6];   // t_wq
    pp.w[1]  = (const float*)d_in[7];   // t_wk
    pp.w[2]  = (const float*)d_in[8];   // t_wv
    pp.w[3]  = (const float*)d_in[24];  // rt_wv
    pp.w[4]  = (const float*)d_in[25];  // tube_wq
    pp.w[5]  = (const float*)d_in[26];  // tube_wk
    pp.w[6]  = (const float*)d_in[27];  // tube_wv
    pp.w[7]  = (const float*)d_in[9];   // geo_wq
    pp.w[8]  = (const float*)d_in[10];  // geo_wk
    pp.w[9]  = (const float*)d_in[11];  // geo_wv
    pp.w[10] = (const float*)d_in[18];  // sem_wq
    pp.w[11] = (const float*)d_in[19];  // sem_wk
    pp.w[12] = (const float*)d_in[20];  // sem_wv
    pp.w[13] = (const float*)d_in[21];  // rnd_wq
    pp.w[14] = (const float*)d_in[22];  // rnd_wk
    pp.w[15] = (const float*)d_in[23];  // rnd_wv
    pp.pw    = (const float*)d_in[28];  // proj_w
    pp.msk[0] = d_in[3];
    pp.msk[1] = d_in[4];
    pp.msk[2] = d_in[5];

    pack_kernel<<<dim3(204), dim3(256), 0, stream>>>(pp, ws);
    proj_gemm_mfma<<<dim3(384), dim3(256), 0, stream>>>(x, ws);
    gemm_tile<<<dim3(384, 1), dim3(256), 0, stream>>>(xp, (const float*)d_in[12],
              (const float*)d_in[13], ws + OFF_PQ, 128, 64);
    gemm_tile<<<dim3(12, 1), dim3(256), 0, stream>>>(pkeys, (const float*)d_in[14],
              (const float*)d_in[15], ws + OFF_PK, 128, 64);
    gemm_tile<<<dim3(12, 1), dim3(256), 0, stream>>>(pkeys, (const float*)d_in[16],
              (const float*)d_in[17], ws + OFF_PV, 128, 64);
    pattern_kadd<<<dim3(48, 2), dim3(256), 0, stream>>>(ws);
    spatial_attn_mfma<<<dim3(768), dim3(256), 0, stream>>>(ws);
    temporal_attn<<<dim3(1536), dim3(64), 0, stream>>>(ws);
    final_gemm_mfma<<<dim3(384), dim3(256), 0, stream>>>((const float*)d_in[29], ws, out);
}